// Round 12
// baseline (239.855 us; speedup 1.0000x reference)
//
#include <hip/hip_runtime.h>
#include <hip/hip_bf16.h>
#include <stdint.h>

// ---------------------------------------------------------------------------
// pcnn round 12: tap-major row-blocked conv + 4-wave blocks w/ LDS weights.
//  - Wave = 16 patches (same verified MFMA mapping/kperm chain as R9-R11).
//  - Conv inner order: per output row r, per tap t: 2 ds_read A-frags then
//    up to 10 MFMAs into round-robin accs (reuse distance ~160cyc >> latency)
//    -> back-to-back MFMA issue with only ~40 acc VGPRs live.
//  - 256-thr block: 4 waves share LDS weight buffers, ping-pong Wb0/Wb1
//    (compile-time parity), next layer prefetched to regs during current
//    layer, ds-written at layer end, one barrier per layer.
//  - LDS ~62KB -> 2 blocks/CU -> 2 waves/SIMD co-resident.
// ---------------------------------------------------------------------------

typedef short bf16x8 __attribute__((ext_vector_type(8)));
typedef float f32x4  __attribute__((ext_vector_type(4)));

// d_ws: WALL bf16 [8 layers][9 taps][32 o(permuted rows)][32 c] @0 (73728 u16)
//   l=0: conv0 (c<8), l=1..6: mid, l=7: logits (natural rows, o<6)
// f32 @ byte 147456: BALL[8][32](perm) @0, WPOST[18][3][25] @256, BPOST[18] @1606
#define WSB_N     73728
#define WSF_BYTE  147456
#define WSF_BALL  0
#define WSF_WPOST 256
#define WSF_BPOST 1606
#define WSF_N     1624

#define NTHR 256
// LDS map (bytes). U region reused: stage(4x6400) -> Wb0|Wb1 -> smb(4x9600)
#define LDS_WB0   0
#define LDS_WB1   18432
#define LDS_IN3   38400   // f32 [4][1200]
#define LDS_COLB  57600   // f32 [4][288]
#define LDS_TOT   62208

__device__ __forceinline__ float b2f(unsigned short u) {
  union { unsigned int u; float f; } v; v.u = ((unsigned int)u) << 16; return v.f;
}
__device__ __forceinline__ unsigned short f2b(float f) {
  union { float f; unsigned int u; } v; v.f = f;
  unsigned int r = v.u + 0x7fffu + ((v.u >> 16) & 1u);  // RNE
  return (unsigned short)(r >> 16);
}
__device__ __forceinline__ unsigned int pk2(float lo, float hi) {
  __hip_bfloat162 h = __float22bfloat162_rn(make_float2(lo, hi));
  union { __hip_bfloat162 h; unsigned int u; } v; v.h = h; return v.u;
}
__device__ __forceinline__ bool sniff_is_f32(const void* w0raw) {
  const unsigned short* q = (const unsigned short*)w0raw;
  int hits = 0;
  #pragma unroll
  for (int i = 0; i < 64; ++i) {
    unsigned int e = (q[i] >> 7) & 0xFFu;
    if (e >= 130u) ++hits;
  }
  return hits > 0;
}
__device__ __forceinline__ float ldw(const void* p, long idx, bool f32) {
  return f32 ? ((const float*)p)[idx] : b2f(((const unsigned short*)p)[idx]);
}
// C-row m -> B-k-slot permutation
__device__ __forceinline__ int kperm(int m) {
  return (m < 16) ? ((m >> 2) * 8 + (m & 3))
                  : (((m - 16) >> 2) * 8 + 4 + (m & 3));
}

// ---------------- weight pre-pack (identical to R9-R11, verified) ----------
__global__ void prep_weights(const void* __restrict__ w0,
                             const void* __restrict__ b0,
                             const void* __restrict__ wm,
                             const void* __restrict__ bm,
                             const void* __restrict__ wl,
                             const void* __restrict__ bl,
                             const void* __restrict__ wp,
                             const void* __restrict__ bp,
                             unsigned short* __restrict__ wsb,
                             float* __restrict__ wsf) {
  const bool f32 = sniff_is_f32(w0);
  int e = blockIdx.x * blockDim.x + threadIdx.x;
  if (e < WSB_N) {                        // WALL[l][t][o32][c32]
    int l = e / 9216, r = e % 9216, t = r / 1024, r2 = r % 1024;
    int o = r2 >> 5, c = r2 & 31;
    float v = 0.f;
    if (l < 7) {
      int co = kperm(o);
      if (co < 25) {
        if (l == 0) { if (c < 8)  v = ldw(w0, (co * 8 + c) * 9 + t, f32); }
        else        { if (c < 25) v = ldw(wm, (((l - 1) * 25 + co) * 25 + c) * 9 + t, f32); }
      }
    } else {
      if (o < 6 && c < 25) v = ldw(wl, (o * 25 + c) * 9 + t, f32);
    }
    wsb[e] = f2b(v);
  } else {
    int q = e - WSB_N;
    if (q < 256) {                        // BALL[l][32]
      int l = q >> 5, m = q & 31;
      float v = 0.f;
      if (l < 7) {
        int co = kperm(m);
        if (co < 25) v = (l == 0) ? ldw(b0, co, f32) : ldw(bm, (l - 1) * 25 + co, f32);
      } else {
        if (m < 6) v = ldw(bl, m, f32);
      }
      wsf[WSF_BALL + q] = v;
    } else if (q < 256 + 1350) {
      wsf[WSF_WPOST + (q - 256)] = ldw(wp, q - 256, f32);
    } else if (q < WSF_N) {
      wsf[WSF_BPOST + (q - 1606)] = ldw(bp, q - 1606, f32);
    }
  }
}

// ---------------- main kernel ----------------------------------------------
__global__ __launch_bounds__(NTHR, 1)
void pcnn_mfma(
    const void* __restrict__ inp,
    const void* __restrict__ w0raw,
    const unsigned short* __restrict__ wsb,
    const float* __restrict__ wsf,
    void* __restrict__ out) {
  __shared__ __align__(16) unsigned char lds[LDS_TOT];

  const bool f32m = sniff_is_f32(w0raw);
  const int tid  = threadIdx.x;
  const int lane = tid & 63;
  const int wv   = tid >> 6;            // wave -> its own 16-patch group
  const int col  = lane & 15;
  const int quad = lane >> 4;
  const long g   = (long)blockIdx.x * 4 + wv;

  const unsigned short* WB0 = (const unsigned short*)(lds + LDS_WB0);
  const unsigned short* WB1 = (const unsigned short*)(lds + LDS_WB1);
  short* stage = (short*)lds + wv * 3200;             // overlays Wb region
  float* in3   = (float*)(lds + LDS_IN3) + wv * 1200;
  float* colb  = (float*)(lds + LDS_COLB) + wv * 288;
  float* smb   = (float*)lds + wv * 2400;             // overlays Wb after logits

  // ---- stage input [b][8c][25px] -> stage[px][b][c8] + in3 (f32) ----
  for (int e = lane; e < 3200; e += 64) {
    int b = e / 200, r = e % 200, c = r / 25, px = r % 25;
    float v = ldw(inp, g * 3200 + e, f32m);
    stage[px * 128 + b * 8 + c] = f2b(v);
    if (c < 3) in3[b * 75 + c * 25 + px] = v;
  }
  __asm__ volatile("s_waitcnt lgkmcnt(0)" ::: "memory");

  // ---- layer-0 B-frags: quad0 holds ch0..7, other quads zero ----
  bf16x8 X[25], Y[25];
  #pragma unroll
  for (int p = 0; p < 25; ++p) {
    union { bf16x8 v; uint4 q4; } t;
    t.q4 = make_uint4(0u, 0u, 0u, 0u);
    if (quad == 0) t.q4 = *(const uint4*)(stage + p * 128 + col * 8);
    X[p] = t.v;
  }

  // ---- weight prefetch pipeline helpers (1152 uint4 per layer) ----
  uint4 P[5];
  auto pload = [&](int l) {
    const uint4* src = (const uint4*)wsb + l * 1152;
    #pragma unroll
    for (int k = 0; k < 5; ++k) { int i = tid + k * 256; if (i < 1152) P[k] = src[i]; }
  };
  auto pstore = [&](int wbofs) {
    uint4* d = (uint4*)(lds + wbofs);
    #pragma unroll
    for (int k = 0; k < 5; ++k) { int i = tid + k * 256; if (i < 1152) d[i] = P[k]; }
  };

  // ---- conv layer: tap-major per output row ----
  auto conv = [&](const bf16x8 (&IN)[25], bf16x8 (&OUT)[25],
                  const unsigned short* Wb, int l) {
    const f32x4 bias0 = *(const f32x4*)(wsf + WSF_BALL + l * 32 + quad * 4);
    const f32x4 bias1 = *(const f32x4*)(wsf + WSF_BALL + l * 32 + 16 + quad * 4);
    #pragma unroll
    for (int r = 0; r < 5; ++r) {
      f32x4 acc0[5], acc1[5];
      #pragma unroll
      for (int px = 0; px < 5; ++px) { acc0[px] = bias0; acc1[px] = bias1; }
      #pragma unroll
      for (int dy = -1; dy <= 1; ++dy) {
        const int ir = r + dy;
        if (ir >= 0 && ir < 5) {
          #pragma unroll
          for (int dx = -1; dx <= 1; ++dx) {
            const int t = (dy + 1) * 3 + (dx + 1);
            bf16x8 A0 = *(const bf16x8*)(Wb + t * 1024 + col * 32 + quad * 8);
            bf16x8 A1 = *(const bf16x8*)(Wb + t * 1024 + (16 + col) * 32 + quad * 8);
            #pragma unroll
            for (int px = 0; px < 5; ++px) {
              const int nx = px + dx;
              if (nx >= 0 && nx < 5) {
                acc0[px] = __builtin_amdgcn_mfma_f32_16x16x32_bf16(A0, IN[ir * 5 + nx], acc0[px], 0, 0, 0);
                acc1[px] = __builtin_amdgcn_mfma_f32_16x16x32_bf16(A1, IN[ir * 5 + nx], acc1[px], 0, 0, 0);
              }
            }
          }
        }
      }
      #pragma unroll
      for (int px = 0; px < 5; ++px) {   // relu+pack -> next layer B-frag
        union { bf16x8 v; unsigned int uu[4]; } nb;
        nb.uu[0] = pk2(fmaxf(acc0[px][0], 0.f), fmaxf(acc0[px][1], 0.f));
        nb.uu[1] = pk2(fmaxf(acc0[px][2], 0.f), fmaxf(acc0[px][3], 0.f));
        nb.uu[2] = pk2(fmaxf(acc1[px][0], 0.f), fmaxf(acc1[px][1], 0.f));
        nb.uu[3] = pk2(fmaxf(acc1[px][2], 0.f), fmaxf(acc1[px][3], 0.f));
        OUT[r * 5 + px] = nb.v;
      }
    }
  };

  // ---- weight pipeline + 7 conv layers (compile-time Wb parity) ----
  pload(0);
  __syncthreads();            // all stage reads done before Wb overwrite
  pstore(LDS_WB0);
  pload(1);
  __syncthreads();
  conv(X, Y, WB0, 0); pstore(LDS_WB1); pload(2); __syncthreads();
  conv(Y, X, WB1, 1); pstore(LDS_WB0); pload(3); __syncthreads();
  conv(X, Y, WB0, 2); pstore(LDS_WB1); pload(4); __syncthreads();
  conv(Y, X, WB1, 3); pstore(LDS_WB0); pload(5); __syncthreads();
  conv(X, Y, WB0, 4); pstore(LDS_WB1); pload(6); __syncthreads();
  conv(Y, X, WB1, 5); pstore(LDS_WB0); pload(7); __syncthreads();
  conv(X, Y, WB0, 6); pstore(LDS_WB1);           __syncthreads();
  // final hidden in Y; logits weights in WB1

  // ---- logits: hoist A-frags, barrier (smb overlays Wb), compute ----
  bf16x8 AL[9];
  #pragma unroll
  for (int t = 0; t < 9; ++t)
    AL[t] = *(const bf16x8*)(WB1 + t * 1024 + col * 32 + quad * 8);
  const f32x4 biasl = *(const f32x4*)(wsf + WSF_BALL + 7 * 32 + quad * 4);
  __syncthreads();            // all Wb reads done; smb region now writable

  #pragma unroll
  for (int p = 0; p < 25; ++p) {
    const int py = p / 5, pxx = p % 5;
    f32x4 a = biasl;
    #pragma unroll
    for (int dy = -1; dy <= 1; ++dy)
      #pragma unroll
      for (int dx = -1; dx <= 1; ++dx)
        if ((unsigned)(py + dy) < 5u && (unsigned)(pxx + dx) < 5u) {
          const int t = (dy + 1) * 3 + (dx + 1);
          a = __builtin_amdgcn_mfma_f32_16x16x32_bf16(AL[t], Y[p + dy * 5 + dx], a, 0, 0, 0);
        }
    float l4 = __shfl_xor(a[0], 16);
    float l5 = __shfl_xor(a[1], 16);
    if (quad == 0) {
      float m = fmaxf(fmaxf(fmaxf(a[0], a[1]), fmaxf(a[2], a[3])), fmaxf(l4, l5));
      float e0 = __expf(a[0] - m), e1 = __expf(a[1] - m), e2 = __expf(a[2] - m);
      float e3 = __expf(a[3] - m), e4 = __expf(l4 - m), e5 = __expf(l5 - m);
      float inv = 1.f / (e0 + e1 + e2 + e3 + e4 + e5);
      float* sp = smb + p * 96 + col * 6;
      sp[0] = e0 * inv; sp[1] = e1 * inv; sp[2] = e2 * inv;
      sp[3] = e3 * inv; sp[4] = e4 * inv; sp[5] = e5 * inv;
    }
  }
  __asm__ volatile("s_waitcnt lgkmcnt(0)" ::: "memory");

  // ---- colors: 5x5 VALID conv on first 3 input channels (from in3) ----
  for (int j = lane; j < 288; j += 64) {
    int b = j / 18, oc = j % 18;
    float s = wsf[WSF_BPOST + oc];
    #pragma unroll
    for (int ic = 0; ic < 3; ++ic)
      #pragma unroll
      for (int px = 0; px < 25; ++px)
        s = fmaf(wsf[WSF_WPOST + (oc * 3 + ic) * 25 + px], in3[b * 75 + ic * 25 + px], s);
    colb[b * 18 + oc] = s;
  }
  __asm__ volatile("s_waitcnt lgkmcnt(0)" ::: "memory");

  // ---- mix + store: out[b][c][p] = sum_w colors[b][c*6+w] * sm[p][b][w] ----
  for (int e = lane; e < 1200; e += 64) {
    int b = e / 75, r = e % 75, c = r / 25, p = r % 25;
    float v = 0.f;
    #pragma unroll
    for (int w = 0; w < 6; ++w)
      v = fmaf(colb[b * 18 + c * 6 + w], smb[p * 96 + b * 6 + w], v);
    const long oidx = g * 1200 + e;
    if (f32m) ((float*)out)[oidx] = v;
    else      ((unsigned short*)out)[oidx] = f2b(v);
  }
}

extern "C" void kernel_launch(void* const* d_in, const int* in_sizes, int n_in,
                              void* d_out, int out_size, void* d_ws, size_t ws_size,
                              hipStream_t stream) {
  unsigned short* wsb = (unsigned short*)d_ws;
  float* wsf = (float*)((char*)d_ws + WSF_BYTE);
  const int B = in_sizes[0] / 200;  // 32768

  const int prep_n = WSB_N + WSF_N;  // 75352
  prep_weights<<<(prep_n + 255) / 256, 256, 0, stream>>>(
      d_in[1], d_in[2], d_in[3], d_in[4], d_in[5], d_in[6], d_in[7], d_in[8],
      wsb, wsf);
  pcnn_mfma<<<B / 64, NTHR, 0, stream>>>(d_in[0], d_in[1], wsb, wsf, d_out);
}